// Round 4
// baseline (815.960 us; speedup 1.0000x reference)
//
#include <hip/hip_runtime.h>
#include <stdint.h>

#define T_TOK 8192
#define HD 1024
#define ED 8
#define DD 2048
#define BM 128
#define BK 32
#define TILE_SHARED 64   // T_TOK/BM shared-expert tiles
#define TILE_MAX 200     // 64 shared + max 136 routed tiles
#define ROWCAP 25600     // 8192 shared + 17408 padded routed rows
#define RT_TPW 8         // router: tokens per wave (32/block, 256 blocks)

typedef short short8 __attribute__((ext_vector_type(8)));
typedef float f32x4 __attribute__((ext_vector_type(4)));

__device__ __forceinline__ unsigned short f2bf(float f) {
  union { float f; unsigned int u; } v; v.f = f;
  unsigned int r = (v.u + 0x7fffu + ((v.u >> 16) & 1u)) >> 16;
  return (unsigned short)r;
}

__device__ __forceinline__ void gll16(const void* g, void* l) {
  __builtin_amdgcn_global_load_lds(
      (const __attribute__((address_space(1))) unsigned int*)g,
      (__attribute__((address_space(3))) unsigned int*)l, 16, 0, 0);
}

// ---------------- zero d_out ----------------
__global__ __launch_bounds__(256) void k_zero(float* __restrict__ outp) {
  size_t i = (size_t)blockIdx.x * 256 + threadIdx.x;
  ((float4*)outp)[i] = make_float4(0.f, 0.f, 0.f, 0.f);
}

// ---------------- init: counts + default assignment table ----------------
__global__ __launch_bounds__(256) void k_init(int* counts, int* tok, float* wrow) {
  int i = blockIdx.x * 256 + threadIdx.x;
  if (i < 32) counts[i] = 0;
  if (i < ROWCAP) {
    tok[i] = (i < T_TOK) ? i : 0;          // shared segment = identity; pads -> token 0
    wrow[i] = (i < T_TOK) ? 1.0f : 0.0f;   // shared weight 1, pads weight 0
  }
}

// ---------------- transpose+convert: in[R][C] fp32 -> out[C][R] bf16 ----------------
__global__ __launch_bounds__(256) void k_transpose(const float* __restrict__ in,
    unsigned short* __restrict__ outp, int R, int C) {
  __shared__ float tile[32][33];
  size_t boff = (size_t)blockIdx.z * (size_t)R * (size_t)C;
  in += boff; outp += boff;
  int c0 = blockIdx.x * 32, r0 = blockIdx.y * 32;
  int tx = threadIdx.x & 31, ty = threadIdx.x >> 5;
#pragma unroll
  for (int i = 0; i < 4; ++i)
    tile[ty + i * 8][tx] = in[(size_t)(r0 + ty + i * 8) * C + c0 + tx];
  __syncthreads();
#pragma unroll
  for (int i = 0; i < 4; ++i)
    outp[(size_t)(c0 + ty + i * 8) * R + r0 + tx] = f2bf(tile[tx][ty + i * 8]);
}

// ---------------- router: x->bf16, logits, softmax, top2, LDS histogram ----------------
__global__ __launch_bounds__(256) void k_router(const float* __restrict__ x,
    const float* __restrict__ Wr, unsigned short* __restrict__ xb,
    int* __restrict__ counts, int* __restrict__ topE, float* __restrict__ topW) {
  __shared__ float wrT[ED * HD];  // [e][h]
  __shared__ int hist[ED];
  int tid = threadIdx.x;
  if (tid < ED) hist[tid] = 0;
  for (int i = tid; i < ED * HD; i += 256) {
    int e = i >> 10, h = i & (HD - 1);
    wrT[i] = Wr[h * ED + e];
  }
  __syncthreads();
  int lane = tid & 63, wave = tid >> 6;
  int tbase = (blockIdx.x * 4 + wave) * RT_TPW;
  for (int tt = 0; tt < RT_TPW; ++tt) {
    int t = tbase + tt;
    const float* xrow = x + (size_t)t * HD;
    unsigned short* xbrow = xb + (size_t)t * HD;
    float acc[ED] = {0, 0, 0, 0, 0, 0, 0, 0};
#pragma unroll
    for (int i = 0; i < HD / 64; ++i) {
      int h = i * 64 + lane;
      float v = xrow[h];
      xbrow[h] = f2bf(v);
#pragma unroll
      for (int e = 0; e < ED; ++e) acc[e] += v * wrT[e * HD + h];
    }
#pragma unroll
    for (int off = 32; off; off >>= 1)
#pragma unroll
      for (int e = 0; e < ED; ++e) acc[e] += __shfl_xor(acc[e], off);
    if (lane == 0) {
      float m = acc[0];
#pragma unroll
      for (int e = 1; e < ED; ++e) m = fmaxf(m, acc[e]);
      float p[ED], s = 0.f;
#pragma unroll
      for (int e = 0; e < ED; ++e) { p[e] = __expf(acc[e] - m); s += p[e]; }
      int i0 = 0;
#pragma unroll
      for (int e = 1; e < ED; ++e) if (acc[e] > acc[i0]) i0 = e;
      int i1 = -1;
#pragma unroll
      for (int e = 0; e < ED; ++e) {
        if (e == i0) continue;
        if (i1 < 0 || acc[e] > acc[i1]) i1 = e;
      }
      float p0 = p[i0] / s, p1 = p[i1] / s;
      float rs = p0 + p1 + 1e-20f;
      topE[t * 2] = i0; topE[t * 2 + 1] = i1;
      topW[t * 2] = p0 / rs; topW[t * 2 + 1] = p1 / rs;
      atomicAdd(&hist[i0], 1);   // LDS atomic — bank speed
      atomicAdd(&hist[i1], 1);
    }
  }
  __syncthreads();
  if (tid < ED) atomicAdd(&counts[tid], hist[tid]);  // 8 global atomics/block
}

// ---------------- plan: segment bases, cursors, tile table ----------------
__global__ __launch_bounds__(256) void k_plan(const int* __restrict__ counts, int* cursor,
    int* __restrict__ tileE, int* __restrict__ tileEnd) {
  __shared__ int tstart[ED + 1], segend[ED];
  if (threadIdx.x == 0) {
    int base = T_TOK, rt = TILE_SHARED;
    for (int e = 0; e < ED; ++e) {
      int c = counts[e];
      cursor[e] = base;
      tstart[e] = rt;
      segend[e] = base + c;
      int tiles = (c + BM - 1) >> 7;
      rt += tiles;
      base += tiles << 7;
    }
    tstart[ED] = rt;
  }
  __syncthreads();
  for (int rt = threadIdx.x; rt < TILE_MAX; rt += 256) {
    int e = -1, end = 0;
    if (rt < TILE_SHARED) { e = ED; end = T_TOK; }
    else {
      for (int q = 0; q < ED; ++q)
        if (rt >= tstart[q] && rt < tstart[q + 1]) { e = q; end = segend[q]; }
    }
    tileE[rt] = e; tileEnd[rt] = end;
  }
}

// ---------------- scatter: block-aggregated cursor allocation ----------------
__global__ __launch_bounds__(256) void k_scatter(const int* __restrict__ topE,
    const float* __restrict__ topW, int* cursor, int* tok, float* wrow) {
  __shared__ int lcount[ED], lbase[ED];
  int tid = threadIdx.x;
  if (tid < ED) lcount[tid] = 0;
  __syncthreads();
  int t = blockIdx.x * 256 + tid;
  int e0 = topE[t * 2], e1 = topE[t * 2 + 1];
  float w0 = topW[t * 2], w1 = topW[t * 2 + 1];
  int s0 = atomicAdd(&lcount[e0], 1);   // LDS
  int s1 = atomicAdd(&lcount[e1], 1);   // LDS
  __syncthreads();
  if (tid < ED) lbase[tid] = atomicAdd(&cursor[tid], lcount[tid]);  // global, 8/block
  __syncthreads();
  int p0 = lbase[e0] + s0;
  int p1 = lbase[e1] + s1;
  tok[p0] = t; wrow[p0] = w0;
  tok[p1] = t; wrow[p1] = w1;
}

// LDS bank-conflict swizzle (R4): slot(row,c) = c ^ ((row>>1)&3).
// Staging lane fetches global k-chunk (lane&3)^((lane>>3)&3); fragment reads use
// lane-constant slot (lane>>4)^((lane>>1)&3). 2 lanes/bank (free, m136).
//
// R8 = R7 resubmit (R3 bench was a container-level infra failure; kernel
// re-audited: uniform barriers, safe buffer rotation, 120KB LDS < 160KB,
// ~232 regs/wave < 256 @ launch_bounds(512,2)).
// k_gemm1: m201-style phase schedule. 128x256 tile, 8 waves (64x64 each,
// acc = 128 AGPR), BK=32, triple-buffered LDS (depth-2 prefetch):
//   P0: ds_read af+bgf | stage(t+2: A,Bg) | bar | lgkm0 | prio1 16xMFMA g | bar
//   P1: ds_read buf    | stage(t+2: Bu)   | vmcnt(5) | bar | lgkm0 | prio1 16xMFMA u | bar
// Counted vmcnt(5) once per K-tile (never 0 mid-loop): proves tile t+1 landed
// block-wide (per-wave vmcnt + barrier), t+2 stays in flight.

// ---------------- GEMM1: hidden = silu(Xg)*(Xu), gathered rows ----------------
__global__ __launch_bounds__(512, 2) void k_gemm1(
    const unsigned short* __restrict__ xb,
    const unsigned short* __restrict__ wgt, const unsigned short* __restrict__ wut,
    const unsigned short* __restrict__ sgt, const unsigned short* __restrict__ sut,
    const int* __restrict__ tok, const int* __restrict__ tileE,
    const int* __restrict__ tileEnd, unsigned short* __restrict__ hbuf, int tileBase) {
  int lt = blockIdx.y;
  int rt = tileBase + lt;
  int e = tileE[rt];
  if (e < 0) return;
  int n0 = blockIdx.x * 256;        // 256-wide N tile
  int grow0 = rt * BM;              // global assignment-row base
  int hrow0 = lt * BM;              // chunk-local hbuf row base
  int segEnd = tileEnd[rt];
  const unsigned short* bg = (e == ED) ? sgt : wgt + (size_t)e * DD * HD;
  const unsigned short* bu = (e == ED) ? sut : wut + (size_t)e * DD * HD;

  __shared__ __align__(16) unsigned short As3[3][4096];   // 128x32 per buf
  __shared__ __align__(16) unsigned short Bg3[3][8192];   // 256x32 per buf
  __shared__ __align__(16) unsigned short Bu3[3][8192];

  int tid = threadIdx.x, lane = tid & 63, wave = tid >> 6;  // 8 waves
  int wm = (wave >> 2) * 64, wn = (wave & 3) * 64;          // 2x4 wave grid
  int kc = (lane & 3) ^ ((lane >> 3) & 3);
  int rl = lane >> 2;

  // staging pointers: wave stages A chunk[wave] (16 rows), Bg/Bu chunks 2w,2w+1
  const unsigned short* pA  = xb + (size_t)tok[grow0 + wave * 16 + rl] * HD + kc * 8;
  const unsigned short* pG0 = bg + (size_t)(n0 + wave * 32 + rl) * HD + kc * 8;
  const unsigned short* pG1 = pG0 + (size_t)16 * HD;
  const unsigned short* pU0 = bu + (size_t)(n0 + wave * 32 + rl) * HD + kc * 8;
  const unsigned short* pU1 = pU0 + (size_t)16 * HD;
  int dA = wave * 512;        // short offsets within a buffer
  int dB0 = wave * 1024, dB1 = wave * 1024 + 512;

  f32x4 zero = {0.f, 0.f, 0.f, 0.f};
  f32x4 accg[4][4], accu[4][4];
#pragma unroll
  for (int i = 0; i < 4; ++i)
#pragma unroll
    for (int j = 0; j < 4; ++j) { accg[i][j] = zero; accu[i][j] = zero; }

  int m15 = lane & 15;
  int sl8 = (((lane >> 4) ^ ((lane >> 1) & 3)) * 8);

  // ---- prologue: stage tiles 0,1 into buffers 0,1 (5 loads each/wave) ----
  gll16(pA,       &As3[0][dA]);
  gll16(pG0,      &Bg3[0][dB0]);
  gll16(pG1,      &Bg3[0][dB1]);
  gll16(pU0,      &Bu3[0][dB0]);
  gll16(pU1,      &Bu3[0][dB1]);
  __builtin_amdgcn_sched_barrier(0);
  gll16(pA + BK,  &As3[1][dA]);
  gll16(pG0 + BK, &Bg3[1][dB0]);
  gll16(pG1 + BK, &Bg3[1][dB1]);
  gll16(pU0 + BK, &Bu3[1][dB0]);
  gll16(pU1 + BK, &Bu3[1][dB1]);
  __builtin_amdgcn_sched_barrier(0);
  asm volatile("s_waitcnt vmcnt(5)" ::: "memory");   // tile0 landed (tile1 in flight)
  __builtin_amdgcn_sched_barrier(0);
  __builtin_amdgcn_s_barrier();

  int b = 0, bs = 2;
  const int NT = HD / BK;   // 32 K-tiles
  for (int t = 0; t < NT; ++t) {
    bool pf = (t + 2 < NT);
    int k2 = (t + 2) * BK;
    const unsigned short* Ab = As3[b];
    const unsigned short* Gb = Bg3[b];
    const unsigned short* Ub = Bu3[b];

    // ---- phase 0: A+Bg fragments, stage t+2 (A,Bg), MFMA accg ----
    short8 af[4], bgf[4];
#pragma unroll
    for (int i = 0; i < 4; ++i) {
      af[i]  = *(const short8*)(Ab + (wm + i * 16 + m15) * BK + sl8);
      bgf[i] = *(const short8*)(Gb + (wn + i * 16 + m15) * BK + sl8);
    }
    if (pf) {
      gll16(pA + k2,  &As3[bs][dA]);
      gll16(pG0 + k2, &Bg3[bs][dB0]);
      gll16(pG1 + k2, &Bg3[bs][dB1]);
    }
    __builtin_amdgcn_sched_barrier(0);
    __builtin_amdgcn_s_barrier();
    asm volatile("s_waitcnt lgkmcnt(0)" ::: "memory");
    __builtin_amdgcn_sched_barrier(0);
    __builtin_amdgcn_s_setprio(1);
#pragma unroll
    for (int i = 0; i < 4; ++i)
#pragma unroll
      for (int j = 0; j < 4; ++j)
        accg[i][j] = __builtin_amdgcn_mfma_f32_16x16x32_bf16(af[i], bgf[j], accg[i][j], 0, 0, 0);
    __builtin_amdgcn_s_setprio(0);
    __builtin_amdgcn_sched_barrier(0);
    __builtin_amdgcn_s_barrier();

    // ---- phase 1: Bu fragments, stage t+2 (Bu), counted vmcnt, MFMA accu ----
    short8 buf_[4];
#pragma unroll
    for (int j = 0; j < 4; ++j)
      buf_[j] = *(const short8*)(Ub + (wn + j * 16 + m15) * BK + sl8);
    if (pf) {
      gll16(pU0 + k2, &Bu3[bs][dB0]);
      gll16(pU1 + k2, &Bu3[bs][dB1]);
    }
    __builtin_amdgcn_sched_barrier(0);
    if (pf) asm volatile("s_waitcnt vmcnt(5)" ::: "memory");   // t+1 landed; t+2 in flight
    else    asm volatile("s_waitcnt vmcnt(0)" ::: "memory");   // epilogue drain
    __builtin_amdgcn_sched_barrier(0);
    __builtin_amdgcn_s_barrier();
    asm volatile("s_waitcnt lgkmcnt(0)" ::: "memory");
    __builtin_amdgcn_sched_barrier(0);
    __builtin_amdgcn_s_setprio(1);
#pragma unroll
    for (int i = 0; i < 4; ++i)
#pragma unroll
      for (int j = 0; j < 4; ++j)
        accu[i][j] = __builtin_amdgcn_mfma_f32_16x16x32_bf16(af[i], buf_[j], accu[i][j], 0, 0, 0);
    __builtin_amdgcn_s_setprio(0);
    __builtin_amdgcn_sched_barrier(0);
    __builtin_amdgcn_s_barrier();

    b = (b == 2) ? 0 : b + 1;
    bs = (bs == 2) ? 0 : bs + 1;
  }

  int colB = n0 + wn + m15;
  int rowB = wm + ((lane >> 4) << 2);
#pragma unroll
  for (int i = 0; i < 4; ++i)
#pragma unroll
    for (int j = 0; j < 4; ++j)
#pragma unroll
      for (int r = 0; r < 4; ++r) {
        int lr = rowB + i * 16 + r;
        float g = accg[i][j][r], u = accu[i][j][r];
        float h = (grow0 + lr < segEnd) ? (g / (1.0f + __expf(-g))) * u : 0.0f;
        hbuf[(size_t)(hrow0 + lr) * DD + colB + j * 16] = f2bf(h);
      }
}

// ---------------- GEMM2: out[tok] += (hidden @ Wd^T) * wrow (atomic) ----------------
__global__ __launch_bounds__(256, 2) void k_gemm2(
    const unsigned short* __restrict__ hbuf,
    const unsigned short* __restrict__ wdt, const unsigned short* __restrict__ sdt,
    const int* __restrict__ tok, const int* __restrict__ tileE,
    const int* __restrict__ tileEnd, const float* __restrict__ wrow,
    float* __restrict__ outp, int tileBase) {
  int lt = blockIdx.y;
  int rt = tileBase + lt;
  int e = tileE[rt];
  if (e < 0) return;
  int n0 = blockIdx.x * BM;
  int grow0 = rt * BM;
  int hrow0 = lt * BM;
  int segEnd = tileEnd[rt];
  const unsigned short* bd = (e == ED) ? sdt : wdt + (size_t)e * HD * DD;

  __shared__ __align__(16) unsigned short As[3][BM * BK];
  __shared__ __align__(16) unsigned short Bs[3][BM * BK];

  int tid = threadIdx.x, lane = tid & 63, wave = tid >> 6;
  int wm = (wave & 1) * 64, wn = (wave >> 1) * 64;
  int kc = (lane & 3) ^ ((lane >> 3) & 3);

  int ldsU[2];
  const unsigned short *pA[2], *pB[2];
#pragma unroll
  for (int r = 0; r < 2; ++r) {
    int chunk = r * 4 + wave;
    int row = chunk * 16 + (lane >> 2);
    ldsU[r] = chunk * 512;
    pA[r] = hbuf + (size_t)(hrow0 + row) * DD + kc * 8;
    pB[r] = bd + (size_t)(n0 + row) * DD + kc * 8;
  }

  f32x4 zero = {0.f, 0.f, 0.f, 0.f};
  f32x4 acc[4][4];
#pragma unroll
  for (int i = 0; i < 4; ++i)
#pragma unroll
    for (int j = 0; j < 4; ++j) acc[i][j] = zero;

  int m15 = lane & 15;
  int sl8 = (((lane >> 4) ^ ((lane >> 1) & 3)) * 8);

  // prologue: stage tiles 0 and 1 into buffers 0 and 1 (8 loads in flight/wave)
#pragma unroll
  for (int r = 0; r < 2; ++r) {
    gll16(pA[r], &As[0][ldsU[r]]);
    gll16(pB[r], &Bs[0][ldsU[r]]);
  }
#pragma unroll
  for (int r = 0; r < 2; ++r) {
    gll16(pA[r] + BK, &As[1][ldsU[r]]);
    gll16(pB[r] + BK, &Bs[1][ldsU[r]]);
  }

  for (int k0 = 0; k0 < DD; k0 += BK) {
    int ti = k0 >> 5;
    int b  = ti % 3;
    if (k0 + BK < DD) asm volatile("s_waitcnt vmcnt(4)" ::: "memory");
    else              asm volatile("s_waitcnt vmcnt(0)" ::: "memory");
    __builtin_amdgcn_sched_barrier(0);
    __builtin_amdgcn_s_barrier();
    __builtin_amdgcn_sched_barrier(0);
    int k2 = k0 + 2 * BK;
    if (k2 < DD) {
      int b2 = (ti + 2) % 3;
#pragma unroll
      for (int r = 0; r < 2; ++r) {
        gll16(pA[r] + k2, &As[b2][ldsU[r]]);
        gll16(pB[r] + k2, &Bs[b2][ldsU[r]]);
      }
    }
    __builtin_amdgcn_sched_barrier(0);  // keep prefetch issues above compute
    short8 af[4], bf[4];
#pragma unroll
    for (int i = 0; i < 4; ++i) {
      af[i] = *(const short8*)(&As[b][(wm + i * 16 + m15) * BK + sl8]);
      bf[i] = *(const short8*)(&Bs[b][(wn + i * 16 + m15) * BK + sl8]);
    }
#pragma unroll
    for (int i = 0; i < 4; ++i)
#pragma unroll
      for (int j = 0; j < 4; ++j)
        acc[i][j] = __builtin_amdgcn_mfma_f32_16x16x32_bf16(af[i], bf[j], acc[i][j], 0, 0, 0);
    __builtin_amdgcn_sched_barrier(0);
  }

  int colB = n0 + wn + m15;
  int rowB = wm + ((lane >> 4) << 2);
#pragma unroll
  for (int i = 0; i < 4; ++i)
#pragma unroll
    for (int r = 0; r < 4; ++r) {
      int grr = grow0 + rowB + i * 16 + r;
      if (grr < segEnd) {
        float w = wrow[grr];
        size_t ob = (size_t)tok[grr] * HD;
#pragma unroll
        for (int j = 0; j < 4; ++j)
          atomicAdd(&outp[ob + colB + j * 16], acc[i][j][r] * w);
      }
    }
}

extern "C" void kernel_launch(void* const* d_in, const int* in_sizes, int n_in,
                              void* d_out, int out_size, void* d_ws, size_t ws_size,
                              hipStream_t stream) {
  const float* x  = (const float*)d_in[0];
  const float* Wr = (const float*)d_in[1];
  const float* Wg = (const float*)d_in[2];
  const float* Wu = (const float*)d_in[3];
  const float* Wd = (const float*)d_in[4];
  const float* Sg = (const float*)d_in[5];
  const float* Su = (const float*)d_in[6];
  const float* Sd = (const float*)d_in[7];
  float* outp = (float*)d_out;

  // Fixed part of the workspace layout
  size_t fixed = 0;
  auto pad = [](size_t b) { return (b + 255) & ~(size_t)255; };
  fixed += pad((size_t)T_TOK * HD * 2);            // xb
  fixed += pad((size_t)ED * DD * HD * 2) * 3;      // wgt, wut, wdt
  fixed += pad((size_t)DD * HD * 2) * 3;           // sgt, sut, sdt
  fixed += pad((size_t)ROWCAP * 4) * 2;            // tok, wrow
  fixed += pad((size_t)T_TOK * 2 * 4) * 2;         // topE, topW
  fixed += pad(128) * 2 + pad(1024) * 2;           // counts, cursor, tileE, tileEnd
  // Adaptive chunking: single 200-tile pass if hbuf fits, else 2x100.
  int CH = TILE_MAX;
  if (fixed + pad((size_t)CH * BM * DD * 2) > ws_size) CH = TILE_MAX / 2;
  if (fixed + pad((size_t)CH * BM * DD * 2) > ws_size) return;  // diagnostic failure

  char* ws = (char*)d_ws;
  size_t off = 0;
  auto alloc = [&](size_t bytes) -> char* {
    char* p = ws + off;
    off += (bytes + 255) & ~(size_t)255;
    return p;
  };
  unsigned short* xb  = (unsigned short*)alloc((size_t)T_TOK * HD * 2);
  unsigned short* wgt = (unsigned short*)alloc((size_t)ED * DD * HD * 2);
  unsigned short* wut = (unsigned short*)alloc((size_t)ED * DD * HD * 2);
  unsigned short* wdt = (unsigned short*)alloc((size_t)ED * HD * DD * 2);
  unsigned short* sgt = (unsigned short*)alloc((size_t)DD * HD * 2);
  unsigned short* sut = (unsigned short*)alloc((size_t)DD * HD * 2);
  unsigned short* sdt = (unsigned short*)alloc((size_t)HD * DD * 2);
  int* tok       = (int*)alloc((size_t)ROWCAP * 4);
  float* wrow    = (float*)alloc((size_t)ROWCAP * 4);
  int* topE      = (int*)alloc((size_t)T_TOK * 2 * 4);
  float* topW    = (float*)alloc((size_t)T_TOK * 2 * 4);
  int* counts    = (int*)alloc(128);
  int* cursor    = (int*)alloc(128);
  int* tileE     = (int*)alloc(1024);
  int* tileEnd   = (int*)alloc(1024);
  unsigned short* hbuf = (unsigned short*)alloc((size_t)CH * BM * DD * 2);

  k_zero<<<(out_size / 4 + 255) / 256, 256, 0, stream>>>(outp);
  k_init<<<(ROWCAP + 255) / 256, 256, 0, stream>>>(counts, tok, wrow);
  k_transpose<<<dim3(DD / 32, HD / 32, ED), 256, 0, stream>>>(Wg, wgt, HD, DD);
  k_transpose<<<dim3(DD / 32, HD / 32, ED), 256, 0, stream>>>(Wu, wut, HD, DD);
  k_transpose<<<dim3(HD / 32, DD / 32, ED), 256, 0, stream>>>(Wd, wdt, DD, HD);
  k_transpose<<<dim3(DD / 32, HD / 32, 1), 256, 0, stream>>>(Sg, sgt, HD, DD);
  k_transpose<<<dim3(DD / 32, HD / 32, 1), 256, 0, stream>>>(Su, sut, HD, DD);
  k_transpose<<<dim3(HD / 32, DD / 32, 1), 256, 0, stream>>>(Sd, sdt, DD, HD);
  k_router<<<T_TOK / (4 * RT_TPW), 256, 0, stream>>>(x, Wr, xb, counts, topE, topW);
  k_plan<<<1, 256, 0, stream>>>(counts, cursor, tileE, tileEnd);
  k_scatter<<<T_TOK / 256, 256, 0, stream>>>(topE, topW, cursor, tok, wrow);
  for (int cb = 0; cb < TILE_MAX; cb += CH) {
    k_gemm1<<<dim3(DD / 256, CH), 512, 0, stream>>>(xb, wgt, wut, sgt, sut, tok,
                                                    tileE, tileEnd, hbuf, cb);
    k_gemm2<<<dim3(HD / BM, CH), 256, 0, stream>>>(hbuf, wdt, sdt, tok, tileE,
                                                   tileEnd, wrow, outp, cb);
  }
}

// Round 5
// 796.698 us; speedup vs baseline: 1.0242x; 1.0242x over previous
//
#include <hip/hip_runtime.h>
#include <stdint.h>

#define T_TOK 8192
#define HD 1024
#define ED 8
#define DD 2048
#define BM 128
#define BK 32
#define TILE_SHARED 64   // T_TOK/BM shared-expert tiles
#define TILE_MAX 200     // 64 shared + max 136 routed tiles
#define ROWCAP 25600     // 8192 shared + 17408 padded routed rows
#define RT_TPW 8         // router: tokens per wave (32/block, 256 blocks)

typedef short short8 __attribute__((ext_vector_type(8)));
typedef float f32x4 __attribute__((ext_vector_type(4)));

__device__ __forceinline__ unsigned short f2bf(float f) {
  union { float f; unsigned int u; } v; v.f = f;
  unsigned int r = (v.u + 0x7fffu + ((v.u >> 16) & 1u)) >> 16;
  return (unsigned short)r;
}

__device__ __forceinline__ void gll16(const void* g, void* l) {
  __builtin_amdgcn_global_load_lds(
      (const __attribute__((address_space(1))) unsigned int*)g,
      (__attribute__((address_space(3))) unsigned int*)l, 16, 0, 0);
}

// ---------------- zero d_out ----------------
__global__ __launch_bounds__(256) void k_zero(float* __restrict__ outp) {
  size_t i = (size_t)blockIdx.x * 256 + threadIdx.x;
  ((float4*)outp)[i] = make_float4(0.f, 0.f, 0.f, 0.f);
}

// ---------------- init: counts + default assignment table ----------------
__global__ __launch_bounds__(256) void k_init(int* counts, int* tok, float* wrow) {
  int i = blockIdx.x * 256 + threadIdx.x;
  if (i < 32) counts[i] = 0;
  if (i < ROWCAP) {
    tok[i] = (i < T_TOK) ? i : 0;          // shared segment = identity; pads -> token 0
    wrow[i] = (i < T_TOK) ? 1.0f : 0.0f;   // shared weight 1, pads weight 0
  }
}

// ---------------- transpose+convert: in[R][C] fp32 -> out[C][R] bf16 ----------------
__global__ __launch_bounds__(256) void k_transpose(const float* __restrict__ in,
    unsigned short* __restrict__ outp, int R, int C) {
  __shared__ float tile[32][33];
  size_t boff = (size_t)blockIdx.z * (size_t)R * (size_t)C;
  in += boff; outp += boff;
  int c0 = blockIdx.x * 32, r0 = blockIdx.y * 32;
  int tx = threadIdx.x & 31, ty = threadIdx.x >> 5;
#pragma unroll
  for (int i = 0; i < 4; ++i)
    tile[ty + i * 8][tx] = in[(size_t)(r0 + ty + i * 8) * C + c0 + tx];
  __syncthreads();
#pragma unroll
  for (int i = 0; i < 4; ++i)
    outp[(size_t)(c0 + ty + i * 8) * R + r0 + tx] = f2bf(tile[tx][ty + i * 8]);
}

// ---------------- router: x->bf16, logits, softmax, top2, LDS histogram ----------------
__global__ __launch_bounds__(256) void k_router(const float* __restrict__ x,
    const float* __restrict__ Wr, unsigned short* __restrict__ xb,
    int* __restrict__ counts, int* __restrict__ topE, float* __restrict__ topW) {
  __shared__ float wrT[ED * HD];  // [e][h]
  __shared__ int hist[ED];
  int tid = threadIdx.x;
  if (tid < ED) hist[tid] = 0;
  for (int i = tid; i < ED * HD; i += 256) {
    int e = i >> 10, h = i & (HD - 1);
    wrT[i] = Wr[h * ED + e];
  }
  __syncthreads();
  int lane = tid & 63, wave = tid >> 6;
  int tbase = (blockIdx.x * 4 + wave) * RT_TPW;
  for (int tt = 0; tt < RT_TPW; ++tt) {
    int t = tbase + tt;
    const float* xrow = x + (size_t)t * HD;
    unsigned short* xbrow = xb + (size_t)t * HD;
    float acc[ED] = {0, 0, 0, 0, 0, 0, 0, 0};
#pragma unroll
    for (int i = 0; i < HD / 64; ++i) {
      int h = i * 64 + lane;
      float v = xrow[h];
      xbrow[h] = f2bf(v);
#pragma unroll
      for (int e = 0; e < ED; ++e) acc[e] += v * wrT[e * HD + h];
    }
#pragma unroll
    for (int off = 32; off; off >>= 1)
#pragma unroll
      for (int e = 0; e < ED; ++e) acc[e] += __shfl_xor(acc[e], off);
    if (lane == 0) {
      float m = acc[0];
#pragma unroll
      for (int e = 1; e < ED; ++e) m = fmaxf(m, acc[e]);
      float p[ED], s = 0.f;
#pragma unroll
      for (int e = 0; e < ED; ++e) { p[e] = __expf(acc[e] - m); s += p[e]; }
      int i0 = 0;
#pragma unroll
      for (int e = 1; e < ED; ++e) if (acc[e] > acc[i0]) i0 = e;
      int i1 = -1;
#pragma unroll
      for (int e = 0; e < ED; ++e) {
        if (e == i0) continue;
        if (i1 < 0 || acc[e] > acc[i1]) i1 = e;
      }
      float p0 = p[i0] / s, p1 = p[i1] / s;
      float rs = p0 + p1 + 1e-20f;
      topE[t * 2] = i0; topE[t * 2 + 1] = i1;
      topW[t * 2] = p0 / rs; topW[t * 2 + 1] = p1 / rs;
      atomicAdd(&hist[i0], 1);   // LDS atomic — bank speed
      atomicAdd(&hist[i1], 1);
    }
  }
  __syncthreads();
  if (tid < ED) atomicAdd(&counts[tid], hist[tid]);  // 8 global atomics/block
}

// ---------------- plan: segment bases, cursors, tile table ----------------
__global__ __launch_bounds__(256) void k_plan(const int* __restrict__ counts, int* cursor,
    int* __restrict__ tileE, int* __restrict__ tileEnd) {
  __shared__ int tstart[ED + 1], segend[ED];
  if (threadIdx.x == 0) {
    int base = T_TOK, rt = TILE_SHARED;
    for (int e = 0; e < ED; ++e) {
      int c = counts[e];
      cursor[e] = base;
      tstart[e] = rt;
      segend[e] = base + c;
      int tiles = (c + BM - 1) >> 7;
      rt += tiles;
      base += tiles << 7;
    }
    tstart[ED] = rt;
  }
  __syncthreads();
  for (int rt = threadIdx.x; rt < TILE_MAX; rt += 256) {
    int e = -1, end = 0;
    if (rt < TILE_SHARED) { e = ED; end = T_TOK; }
    else {
      for (int q = 0; q < ED; ++q)
        if (rt >= tstart[q] && rt < tstart[q + 1]) { e = q; end = segend[q]; }
    }
    tileE[rt] = e; tileEnd[rt] = end;
  }
}

// ---------------- scatter: block-aggregated cursor allocation ----------------
__global__ __launch_bounds__(256) void k_scatter(const int* __restrict__ topE,
    const float* __restrict__ topW, int* cursor, int* tok, float* wrow) {
  __shared__ int lcount[ED], lbase[ED];
  int tid = threadIdx.x;
  if (tid < ED) lcount[tid] = 0;
  __syncthreads();
  int t = blockIdx.x * 256 + tid;
  int e0 = topE[t * 2], e1 = topE[t * 2 + 1];
  float w0 = topW[t * 2], w1 = topW[t * 2 + 1];
  int s0 = atomicAdd(&lcount[e0], 1);   // LDS
  int s1 = atomicAdd(&lcount[e1], 1);   // LDS
  __syncthreads();
  if (tid < ED) lbase[tid] = atomicAdd(&cursor[tid], lcount[tid]);  // global, 8/block
  __syncthreads();
  int p0 = lbase[e0] + s0;
  int p1 = lbase[e1] + s1;
  tok[p0] = t; wrow[p0] = w0;
  tok[p1] = t; wrow[p1] = w1;
}

// LDS bank-conflict swizzle: slot(row,c) = c ^ ((row>>1)&3).
// Staging lane fetches global k-chunk (lane&3)^((lane>>3)&3); fragment reads use
// lane-constant slot (lane>>4)^((lane>>1)&3). 2 lanes/bank (free, m136).
//
// R9 (occupancy round): R0-R7 post-mortem — three schedules (2-barrier,
// counted-vmcnt dbuf, m201-style phases) all identical at ~300us / 30% MfmaUtil.
// Shared invariant: 2 waves/SIMD (dual 128-AGPR accumulator). m97's 874 TF runs
// 3 waves/SIMD at 164 regs; m114: cross-wave overlap at >=3 waves/SIMD is what
// hides staging latency. Fix: per-wave tile 64x32 per matrix -> accg[4][2]+
// accu[4][2] = 64 AGPR, block 128x64, LDS 48KB, launch_bounds(256,3)
// -> 3 blocks/CU = 12 waves/CU. Schedule: R6 triple-buffer counted vmcnt.

// ---------------- GEMM1: hidden = silu(Xg)*(Xu), gathered rows ----------------
__global__ __launch_bounds__(256, 3) void k_gemm1(
    const unsigned short* __restrict__ xb,
    const unsigned short* __restrict__ wgt, const unsigned short* __restrict__ wut,
    const unsigned short* __restrict__ sgt, const unsigned short* __restrict__ sut,
    const int* __restrict__ tok, const int* __restrict__ tileE,
    const int* __restrict__ tileEnd, unsigned short* __restrict__ hbuf, int tileBase) {
  int lt = blockIdx.y;
  int rt = tileBase + lt;
  int e = tileE[rt];
  if (e < 0) return;
  int n0 = blockIdx.x * 64;         // 64-wide N tile
  int grow0 = rt * BM;              // global assignment-row base
  int hrow0 = lt * BM;              // chunk-local hbuf row base
  int segEnd = tileEnd[rt];
  const unsigned short* bg = (e == ED) ? sgt : wgt + (size_t)e * DD * HD;
  const unsigned short* bu = (e == ED) ? sut : wut + (size_t)e * DD * HD;

  __shared__ __align__(16) unsigned short As[3][BM * BK];   // 8 KB / buf
  __shared__ __align__(16) unsigned short Bg[3][64 * BK];   // 4 KB / buf
  __shared__ __align__(16) unsigned short Bu[3][64 * BK];   // 4 KB / buf

  int tid = threadIdx.x, lane = tid & 63, wave = tid >> 6;  // 4 waves
  int wm = (wave & 1) * 64, wn = (wave >> 1) * 32;          // 2M x 2N wave grid
  int kc = (lane & 3) ^ ((lane >> 3) & 3);   // swizzled global k-chunk for staging
  int rl = lane >> 2;

  // A: wave stages chunks {wave, wave+4} (16 rows each); Bg/Bu: chunk [wave]
  int ldsA[2];
  const unsigned short* pA[2];
#pragma unroll
  for (int r = 0; r < 2; ++r) {
    int chunk = r * 4 + wave;
    ldsA[r] = chunk * 512;
    pA[r] = xb + (size_t)tok[grow0 + chunk * 16 + rl] * HD + kc * 8;
  }
  const unsigned short* pG = bg + (size_t)(n0 + wave * 16 + rl) * HD + kc * 8;
  const unsigned short* pU = bu + (size_t)(n0 + wave * 16 + rl) * HD + kc * 8;
  int dB = wave * 512;

  f32x4 zero = {0.f, 0.f, 0.f, 0.f};
  f32x4 accg[4][2], accu[4][2];
#pragma unroll
  for (int i = 0; i < 4; ++i)
#pragma unroll
    for (int j = 0; j < 2; ++j) { accg[i][j] = zero; accu[i][j] = zero; }

  int m15 = lane & 15;
  int sl8 = (((lane >> 4) ^ ((lane >> 1) & 3)) * 8);  // lane-constant swizzled slot

  // prologue: stage tiles 0 and 1 into buffers 0 and 1 (4 loads each/wave)
  gll16(pA[0],      &As[0][ldsA[0]]);
  gll16(pA[1],      &As[0][ldsA[1]]);
  gll16(pG,         &Bg[0][dB]);
  gll16(pU,         &Bu[0][dB]);
  __builtin_amdgcn_sched_barrier(0);
  gll16(pA[0] + BK, &As[1][ldsA[0]]);
  gll16(pA[1] + BK, &As[1][ldsA[1]]);
  gll16(pG + BK,    &Bg[1][dB]);
  gll16(pU + BK,    &Bu[1][dB]);

  const int NT = HD / BK;   // 32 K-tiles
  for (int t = 0; t < NT; ++t) {
    int b = t % 3;
    // steady state: tiles t (4 loads) + t+1 (4 loads) outstanding; drain t's.
    if (t + 1 < NT) asm volatile("s_waitcnt vmcnt(4)" ::: "memory");
    else            asm volatile("s_waitcnt vmcnt(0)" ::: "memory");
    __builtin_amdgcn_sched_barrier(0);
    __builtin_amdgcn_s_barrier();   // tile t visible block-wide; t-1 reads done
    __builtin_amdgcn_sched_barrier(0);
    int k2 = (t + 2) * BK;
    if (k2 < HD) {
      int b2 = (t + 2) % 3;         // buffer read in iter t-1, now free
      gll16(pA[0] + k2, &As[b2][ldsA[0]]);
      gll16(pA[1] + k2, &As[b2][ldsA[1]]);
      gll16(pG + k2,    &Bg[b2][dB]);
      gll16(pU + k2,    &Bu[b2][dB]);
    }
    __builtin_amdgcn_sched_barrier(0);  // keep prefetch issues above compute
    short8 af[4], bgf[2], buf_[2];
#pragma unroll
    for (int i = 0; i < 4; ++i)
      af[i] = *(const short8*)(&As[b][(wm + i * 16 + m15) * BK + sl8]);
#pragma unroll
    for (int j = 0; j < 2; ++j) {
      bgf[j]  = *(const short8*)(&Bg[b][(wn + j * 16 + m15) * BK + sl8]);
      buf_[j] = *(const short8*)(&Bu[b][(wn + j * 16 + m15) * BK + sl8]);
    }
#pragma unroll
    for (int i = 0; i < 4; ++i)
#pragma unroll
      for (int j = 0; j < 2; ++j) {
        accg[i][j] = __builtin_amdgcn_mfma_f32_16x16x32_bf16(af[i], bgf[j],  accg[i][j], 0, 0, 0);
        accu[i][j] = __builtin_amdgcn_mfma_f32_16x16x32_bf16(af[i], buf_[j], accu[i][j], 0, 0, 0);
      }
    __builtin_amdgcn_sched_barrier(0);
  }

  int colB = n0 + wn + m15;
  int rowB = wm + ((lane >> 4) << 2);
#pragma unroll
  for (int i = 0; i < 4; ++i)
#pragma unroll
    for (int j = 0; j < 2; ++j)
#pragma unroll
      for (int r = 0; r < 4; ++r) {
        int lr = rowB + i * 16 + r;
        float g = accg[i][j][r], u = accu[i][j][r];
        float h = (grow0 + lr < segEnd) ? (g / (1.0f + __expf(-g))) * u : 0.0f;
        hbuf[(size_t)(hrow0 + lr) * DD + colB + j * 16] = f2bf(h);
      }
}

// ---------------- GEMM2: out[tok] += (hidden @ Wd^T) * wrow (atomic) ----------------
__global__ __launch_bounds__(256, 3) void k_gemm2(
    const unsigned short* __restrict__ hbuf,
    const unsigned short* __restrict__ wdt, const unsigned short* __restrict__ sdt,
    const int* __restrict__ tok, const int* __restrict__ tileE,
    const int* __restrict__ tileEnd, const float* __restrict__ wrow,
    float* __restrict__ outp, int tileBase) {
  int lt = blockIdx.y;
  int rt = tileBase + lt;
  int e = tileE[rt];
  if (e < 0) return;
  int n0 = blockIdx.x * BM;
  int grow0 = rt * BM;
  int hrow0 = lt * BM;
  int segEnd = tileEnd[rt];
  const unsigned short* bd = (e == ED) ? sdt : wdt + (size_t)e * HD * DD;

  __shared__ __align__(16) unsigned short As[3][BM * BK];
  __shared__ __align__(16) unsigned short Bs[3][BM * BK];

  int tid = threadIdx.x, lane = tid & 63, wave = tid >> 6;
  int wm = (wave & 1) * 64, wn = (wave >> 1) * 64;
  int kc = (lane & 3) ^ ((lane >> 3) & 3);

  int ldsU[2];
  const unsigned short *pA[2], *pB[2];
#pragma unroll
  for (int r = 0; r < 2; ++r) {
    int chunk = r * 4 + wave;
    int row = chunk * 16 + (lane >> 2);
    ldsU[r] = chunk * 512;
    pA[r] = hbuf + (size_t)(hrow0 + row) * DD + kc * 8;
    pB[r] = bd + (size_t)(n0 + row) * DD + kc * 8;
  }

  f32x4 zero = {0.f, 0.f, 0.f, 0.f};
  f32x4 acc[4][4];
#pragma unroll
  for (int i = 0; i < 4; ++i)
#pragma unroll
    for (int j = 0; j < 4; ++j) acc[i][j] = zero;

  int m15 = lane & 15;
  int sl8 = (((lane >> 4) ^ ((lane >> 1) & 3)) * 8);

  // prologue: stage tiles 0 and 1 into buffers 0 and 1 (8 loads in flight/wave)
#pragma unroll
  for (int r = 0; r < 2; ++r) {
    gll16(pA[r], &As[0][ldsU[r]]);
    gll16(pB[r], &Bs[0][ldsU[r]]);
  }
#pragma unroll
  for (int r = 0; r < 2; ++r) {
    gll16(pA[r] + BK, &As[1][ldsU[r]]);
    gll16(pB[r] + BK, &Bs[1][ldsU[r]]);
  }

  for (int k0 = 0; k0 < DD; k0 += BK) {
    int ti = k0 >> 5;
    int b  = ti % 3;
    if (k0 + BK < DD) asm volatile("s_waitcnt vmcnt(4)" ::: "memory");
    else              asm volatile("s_waitcnt vmcnt(0)" ::: "memory");
    __builtin_amdgcn_sched_barrier(0);
    __builtin_amdgcn_s_barrier();
    __builtin_amdgcn_sched_barrier(0);
    int k2 = k0 + 2 * BK;
    if (k2 < DD) {
      int b2 = (ti + 2) % 3;
#pragma unroll
      for (int r = 0; r < 2; ++r) {
        gll16(pA[r] + k2, &As[b2][ldsU[r]]);
        gll16(pB[r] + k2, &Bs[b2][ldsU[r]]);
      }
    }
    __builtin_amdgcn_sched_barrier(0);  // keep prefetch issues above compute
    short8 af[4], bf[4];
#pragma unroll
    for (int i = 0; i < 4; ++i) {
      af[i] = *(const short8*)(&As[b][(wm + i * 16 + m15) * BK + sl8]);
      bf[i] = *(const short8*)(&Bs[b][(wn + i * 16 + m15) * BK + sl8]);
    }
#pragma unroll
    for (int i = 0; i < 4; ++i)
#pragma unroll
      for (int j = 0; j < 4; ++j)
        acc[i][j] = __builtin_amdgcn_mfma_f32_16x16x32_bf16(af[i], bf[j], acc[i][j], 0, 0, 0);
    __builtin_amdgcn_sched_barrier(0);
  }

  int colB = n0 + wn + m15;
  int rowB = wm + ((lane >> 4) << 2);
#pragma unroll
  for (int i = 0; i < 4; ++i)
#pragma unroll
    for (int r = 0; r < 4; ++r) {
      int grr = grow0 + rowB + i * 16 + r;
      if (grr < segEnd) {
        float w = wrow[grr];
        size_t ob = (size_t)tok[grr] * HD;
#pragma unroll
        for (int j = 0; j < 4; ++j)
          atomicAdd(&outp[ob + colB + j * 16], acc[i][j][r] * w);
      }
    }
}

extern "C" void kernel_launch(void* const* d_in, const int* in_sizes, int n_in,
                              void* d_out, int out_size, void* d_ws, size_t ws_size,
                              hipStream_t stream) {
  const float* x  = (const float*)d_in[0];
  const float* Wr = (const float*)d_in[1];
  const float* Wg = (const float*)d_in[2];
  const float* Wu = (const float*)d_in[3];
  const float* Wd = (const float*)d_in[4];
  const float* Sg = (const float*)d_in[5];
  const float* Su = (const float*)d_in[6];
  const float* Sd = (const float*)d_in[7];
  float* outp = (float*)d_out;

  // Fixed part of the workspace layout
  size_t fixed = 0;
  auto pad = [](size_t b) { return (b + 255) & ~(size_t)255; };
  fixed += pad((size_t)T_TOK * HD * 2);            // xb
  fixed += pad((size_t)ED * DD * HD * 2) * 3;      // wgt, wut, wdt
  fixed += pad((size_t)DD * HD * 2) * 3;           // sgt, sut, sdt
  fixed += pad((size_t)ROWCAP * 4) * 2;            // tok, wrow
  fixed += pad((size_t)T_TOK * 2 * 4) * 2;         // topE, topW
  fixed += pad(128) * 2 + pad(1024) * 2;           // counts, cursor, tileE, tileEnd
  // Adaptive chunking: single 200-tile pass if hbuf fits, else 2x100.
  int CH = TILE_MAX;
  if (fixed + pad((size_t)CH * BM * DD * 2) > ws_size) CH = TILE_MAX / 2;
  if (fixed + pad((size_t)CH * BM * DD * 2) > ws_size) return;  // diagnostic failure

  char* ws = (char*)d_ws;
  size_t off = 0;
  auto alloc = [&](size_t bytes) -> char* {
    char* p = ws + off;
    off += (bytes + 255) & ~(size_t)255;
    return p;
  };
  unsigned short* xb  = (unsigned short*)alloc((size_t)T_TOK * HD * 2);
  unsigned short* wgt = (unsigned short*)alloc((size_t)ED * DD * HD * 2);
  unsigned short* wut = (unsigned short*)alloc((size_t)ED * DD * HD * 2);
  unsigned short* wdt = (unsigned short*)alloc((size_t)ED * HD * DD * 2);
  unsigned short* sgt = (unsigned short*)alloc((size_t)DD * HD * 2);
  unsigned short* sut = (unsigned short*)alloc((size_t)DD * HD * 2);
  unsigned short* sdt = (unsigned short*)alloc((size_t)HD * DD * 2);
  int* tok       = (int*)alloc((size_t)ROWCAP * 4);
  float* wrow    = (float*)alloc((size_t)ROWCAP * 4);
  int* topE      = (int*)alloc((size_t)T_TOK * 2 * 4);
  float* topW    = (float*)alloc((size_t)T_TOK * 2 * 4);
  int* counts    = (int*)alloc(128);
  int* cursor    = (int*)alloc(128);
  int* tileE     = (int*)alloc(1024);
  int* tileEnd   = (int*)alloc(1024);
  unsigned short* hbuf = (unsigned short*)alloc((size_t)CH * BM * DD * 2);

  k_zero<<<(out_size / 4 + 255) / 256, 256, 0, stream>>>(outp);
  k_init<<<(ROWCAP + 255) / 256, 256, 0, stream>>>(counts, tok, wrow);
  k_transpose<<<dim3(DD / 32, HD / 32, ED), 256, 0, stream>>>(Wg, wgt, HD, DD);
  k_transpose<<<dim3(DD / 32, HD / 32, ED), 256, 0, stream>>>(Wu, wut, HD, DD);
  k_transpose<<<dim3(HD / 32, DD / 32, ED), 256, 0, stream>>>(Wd, wdt, DD, HD);
  k_transpose<<<dim3(DD / 32, HD / 32, 1), 256, 0, stream>>>(Sg, sgt, HD, DD);
  k_transpose<<<dim3(DD / 32, HD / 32, 1), 256, 0, stream>>>(Su, sut, HD, DD);
  k_transpose<<<dim3(HD / 32, DD / 32, 1), 256, 0, stream>>>(Sd, sdt, DD, HD);
  k_router<<<T_TOK / (4 * RT_TPW), 256, 0, stream>>>(x, Wr, xb, counts, topE, topW);
  k_plan<<<1, 256, 0, stream>>>(counts, cursor, tileE, tileEnd);
  k_scatter<<<T_TOK / 256, 256, 0, stream>>>(topE, topW, cursor, tok, wrow);
  for (int cb = 0; cb < TILE_MAX; cb += CH) {
    k_gemm1<<<dim3(DD / 64, CH), 256, 0, stream>>>(xb, wgt, wut, sgt, sut, tok,
                                                   tileE, tileEnd, hbuf, cb);
    k_gemm2<<<dim3(HD / BM, CH), 256, 0, stream>>>(hbuf, wdt, sdt, tok, tileE,
                                                   tileEnd, wrow, outp, cb);
  }
}

// Round 6
// 767.312 us; speedup vs baseline: 1.0634x; 1.0383x over previous
//
#include <hip/hip_runtime.h>
#include <stdint.h>

#define T_TOK 8192
#define HD 1024
#define ED 8
#define DD 2048
#define BM 128
#define BK 32
#define TILE_SHARED 64   // T_TOK/BM shared-expert tiles
#define TILE_MAX 200     // 64 shared + max 136 routed tiles
#define ROWCAP 25600     // 8192 shared + 17408 padded routed rows
#define RT_TPW 8         // router: tokens per wave (32/block, 256 blocks)

typedef short short8 __attribute__((ext_vector_type(8)));
typedef unsigned short ushort8 __attribute__((ext_vector_type(8)));
typedef float f32x4 __attribute__((ext_vector_type(4)));

__device__ __forceinline__ unsigned short f2bf(float f) {
  union { float f; unsigned int u; } v; v.f = f;
  unsigned int r = (v.u + 0x7fffu + ((v.u >> 16) & 1u)) >> 16;
  return (unsigned short)r;
}

__device__ __forceinline__ void gll16(const void* g, void* l) {
  __builtin_amdgcn_global_load_lds(
      (const __attribute__((address_space(1))) unsigned int*)g,
      (__attribute__((address_space(3))) unsigned int*)l, 16, 0, 0);
}

// ---------------- zero d_out ----------------
__global__ __launch_bounds__(256) void k_zero(float* __restrict__ outp) {
  size_t i = (size_t)blockIdx.x * 256 + threadIdx.x;
  ((float4*)outp)[i] = make_float4(0.f, 0.f, 0.f, 0.f);
}

// ---------------- init: counts + default assignment table ----------------
__global__ __launch_bounds__(256) void k_init(int* counts, int* tok, float* wrow) {
  int i = blockIdx.x * 256 + threadIdx.x;
  if (i < 32) counts[i] = 0;
  if (i < ROWCAP) {
    tok[i] = (i < T_TOK) ? i : 0;          // shared segment = identity; pads -> token 0
    wrow[i] = (i < T_TOK) ? 1.0f : 0.0f;   // shared weight 1, pads weight 0
  }
}

// ---------------- transpose+convert: in[R][C] fp32 -> out[C][R] bf16 ----------------
// R6: vectorized. 64x64 tile, float4 global loads (16B/lane), LDS [64][65]
// (write phase: lanes hit 64 distinct (row+col) values -> exactly 2-way = free;
// read phase: bank = (8g+q+cc)%32 -> 2-way = free), 16B bf16x8 stores.
__global__ __launch_bounds__(256) void k_transpose(const float* __restrict__ in,
    unsigned short* __restrict__ outp, int R, int C) {
  __shared__ float tile[64][65];
  size_t boff = (size_t)blockIdx.z * (size_t)R * (size_t)C;
  in += boff; outp += boff;
  int c0 = blockIdx.x * 64, r0 = blockIdx.y * 64;
  int tid = threadIdx.x;
  int lr = tid >> 4;             // 0..15
  int lc = (tid & 15) << 2;      // 0,4,...,60
#pragma unroll
  for (int p = 0; p < 4; ++p) {
    int row = lr + p * 16;
    float4 v = *(const float4*)&in[(size_t)(r0 + row) * C + c0 + lc];
    tile[row][lc] = v.x; tile[row][lc + 1] = v.y;
    tile[row][lc + 2] = v.z; tile[row][lc + 3] = v.w;
  }
  __syncthreads();
  int cc = tid >> 2;             // 0..63 output row (= input col)
#pragma unroll
  for (int p = 0; p < 2; ++p) {
    int g = (tid & 3) + p * 4;   // 0..7 -> 8 input rows per store
    int rr = g * 8;
    ushort8 v;
#pragma unroll
    for (int q = 0; q < 8; ++q) v[q] = f2bf(tile[rr + q][cc]);
    *(ushort8*)&outp[(size_t)(c0 + cc) * R + r0 + rr] = v;
  }
}

// ---------------- router: x->bf16, logits, softmax, top2, LDS histogram ----------------
__global__ __launch_bounds__(256) void k_router(const float* __restrict__ x,
    const float* __restrict__ Wr, unsigned short* __restrict__ xb,
    int* __restrict__ counts, int* __restrict__ topE, float* __restrict__ topW) {
  __shared__ float wrT[ED * HD];  // [e][h]
  __shared__ int hist[ED];
  int tid = threadIdx.x;
  if (tid < ED) hist[tid] = 0;
  for (int i = tid; i < ED * HD; i += 256) {
    int e = i >> 10, h = i & (HD - 1);
    wrT[i] = Wr[h * ED + e];
  }
  __syncthreads();
  int lane = tid & 63, wave = tid >> 6;
  int tbase = (blockIdx.x * 4 + wave) * RT_TPW;
  for (int tt = 0; tt < RT_TPW; ++tt) {
    int t = tbase + tt;
    const float* xrow = x + (size_t)t * HD;
    unsigned short* xbrow = xb + (size_t)t * HD;
    float acc[ED] = {0, 0, 0, 0, 0, 0, 0, 0};
#pragma unroll
    for (int i = 0; i < HD / 64; ++i) {
      int h = i * 64 + lane;
      float v = xrow[h];
      xbrow[h] = f2bf(v);
#pragma unroll
      for (int e = 0; e < ED; ++e) acc[e] += v * wrT[e * HD + h];
    }
#pragma unroll
    for (int off = 32; off; off >>= 1)
#pragma unroll
      for (int e = 0; e < ED; ++e) acc[e] += __shfl_xor(acc[e], off);
    if (lane == 0) {
      float m = acc[0];
#pragma unroll
      for (int e = 1; e < ED; ++e) m = fmaxf(m, acc[e]);
      float p[ED], s = 0.f;
#pragma unroll
      for (int e = 0; e < ED; ++e) { p[e] = __expf(acc[e] - m); s += p[e]; }
      int i0 = 0;
#pragma unroll
      for (int e = 1; e < ED; ++e) if (acc[e] > acc[i0]) i0 = e;
      int i1 = -1;
#pragma unroll
      for (int e = 0; e < ED; ++e) {
        if (e == i0) continue;
        if (i1 < 0 || acc[e] > acc[i1]) i1 = e;
      }
      float p0 = p[i0] / s, p1 = p[i1] / s;
      float rs = p0 + p1 + 1e-20f;
      topE[t * 2] = i0; topE[t * 2 + 1] = i1;
      topW[t * 2] = p0 / rs; topW[t * 2 + 1] = p1 / rs;
      atomicAdd(&hist[i0], 1);   // LDS atomic — bank speed
      atomicAdd(&hist[i1], 1);
    }
  }
  __syncthreads();
  if (tid < ED) atomicAdd(&counts[tid], hist[tid]);  // 8 global atomics/block
}

// ---------------- plan: segment bases, cursors, tile table ----------------
__global__ __launch_bounds__(256) void k_plan(const int* __restrict__ counts, int* cursor,
    int* __restrict__ tileE, int* __restrict__ tileEnd) {
  __shared__ int tstart[ED + 1], segend[ED];
  if (threadIdx.x == 0) {
    int base = T_TOK, rt = TILE_SHARED;
    for (int e = 0; e < ED; ++e) {
      int c = counts[e];
      cursor[e] = base;
      tstart[e] = rt;
      segend[e] = base + c;
      int tiles = (c + BM - 1) >> 7;
      rt += tiles;
      base += tiles << 7;
    }
    tstart[ED] = rt;
  }
  __syncthreads();
  for (int rt = threadIdx.x; rt < TILE_MAX; rt += 256) {
    int e = -1, end = 0;
    if (rt < TILE_SHARED) { e = ED; end = T_TOK; }
    else {
      for (int q = 0; q < ED; ++q)
        if (rt >= tstart[q] && rt < tstart[q + 1]) { e = q; end = segend[q]; }
    }
    tileE[rt] = e; tileEnd[rt] = end;
  }
}

// ---------------- scatter: block-aggregated cursor allocation ----------------
__global__ __launch_bounds__(256) void k_scatter(const int* __restrict__ topE,
    const float* __restrict__ topW, int* cursor, int* tok, float* wrow) {
  __shared__ int lcount[ED], lbase[ED];
  int tid = threadIdx.x;
  if (tid < ED) lcount[tid] = 0;
  __syncthreads();
  int t = blockIdx.x * 256 + tid;
  int e0 = topE[t * 2], e1 = topE[t * 2 + 1];
  float w0 = topW[t * 2], w1 = topW[t * 2 + 1];
  int s0 = atomicAdd(&lcount[e0], 1);   // LDS
  int s1 = atomicAdd(&lcount[e1], 1);   // LDS
  __syncthreads();
  if (tid < ED) lbase[tid] = atomicAdd(&cursor[tid], lcount[tid]);  // global, 8/block
  __syncthreads();
  int p0 = lbase[e0] + s0;
  int p1 = lbase[e1] + s1;
  tok[p0] = t; wrow[p0] = w0;
  tok[p1] = t; wrow[p1] = w1;
}

// LDS bank-conflict swizzle: slot(row,c) = c ^ ((row>>1)&3).
// Staging lane fetches global k-chunk (lane&3)^((lane>>3)&3); fragment reads use
// lane-constant slot (lane>>4)^((lane>>1)&3). 2 lanes/bank (free, m136).
//
// R6 additions: bijective XCD swizzle (T1/m204) on both GEMM grids. Dispatch
// order lin = by*NX+bx round-robins XCDs; remap wk = (lin&7)*q + (lin>>3)
// (nwg%8==0 for all CH cases) so each XCD owns a contiguous (y,x) span ->
// A-panels and expert weights fill ONE L2 instead of eight.
// GEMM bodies unchanged from R9 (best so far): 128x64 tile, 4 waves, 64-AGPR
// acc, triple-buffer counted-vmcnt, 3 blocks/CU.

// ---------------- GEMM1: hidden = silu(Xg)*(Xu), gathered rows ----------------
__global__ __launch_bounds__(256, 3) void k_gemm1(
    const unsigned short* __restrict__ xb,
    const unsigned short* __restrict__ wgt, const unsigned short* __restrict__ wut,
    const unsigned short* __restrict__ sgt, const unsigned short* __restrict__ sut,
    const int* __restrict__ tok, const int* __restrict__ tileE,
    const int* __restrict__ tileEnd, unsigned short* __restrict__ hbuf, int tileBase) {
  // XCD swizzle: NX = DD/64 = 32
  int lin = blockIdx.y * 32 + blockIdx.x;
  int q = (32 * gridDim.y) >> 3;
  int wk = (lin & 7) * q + (lin >> 3);
  int bx = wk & 31, by = wk >> 5;

  int lt = by;
  int rt = tileBase + lt;
  int e = tileE[rt];
  if (e < 0) return;
  int n0 = bx * 64;                 // 64-wide N tile
  int grow0 = rt * BM;              // global assignment-row base
  int hrow0 = lt * BM;              // chunk-local hbuf row base
  int segEnd = tileEnd[rt];
  const unsigned short* bg = (e == ED) ? sgt : wgt + (size_t)e * DD * HD;
  const unsigned short* bu = (e == ED) ? sut : wut + (size_t)e * DD * HD;

  __shared__ __align__(16) unsigned short As[3][BM * BK];   // 8 KB / buf
  __shared__ __align__(16) unsigned short Bg[3][64 * BK];   // 4 KB / buf
  __shared__ __align__(16) unsigned short Bu[3][64 * BK];   // 4 KB / buf

  int tid = threadIdx.x, lane = tid & 63, wave = tid >> 6;  // 4 waves
  int wm = (wave & 1) * 64, wn = (wave >> 1) * 32;          // 2M x 2N wave grid
  int kc = (lane & 3) ^ ((lane >> 3) & 3);   // swizzled global k-chunk for staging
  int rl = lane >> 2;

  // A: wave stages chunks {wave, wave+4} (16 rows each); Bg/Bu: chunk [wave]
  int ldsA[2];
  const unsigned short* pA[2];
#pragma unroll
  for (int r = 0; r < 2; ++r) {
    int chunk = r * 4 + wave;
    ldsA[r] = chunk * 512;
    pA[r] = xb + (size_t)tok[grow0 + chunk * 16 + rl] * HD + kc * 8;
  }
  const unsigned short* pG = bg + (size_t)(n0 + wave * 16 + rl) * HD + kc * 8;
  const unsigned short* pU = bu + (size_t)(n0 + wave * 16 + rl) * HD + kc * 8;
  int dB = wave * 512;

  f32x4 zero = {0.f, 0.f, 0.f, 0.f};
  f32x4 accg[4][2], accu[4][2];
#pragma unroll
  for (int i = 0; i < 4; ++i)
#pragma unroll
    for (int j = 0; j < 2; ++j) { accg[i][j] = zero; accu[i][j] = zero; }

  int m15 = lane & 15;
  int sl8 = (((lane >> 4) ^ ((lane >> 1) & 3)) * 8);  // lane-constant swizzled slot

  // prologue: stage tiles 0 and 1 into buffers 0 and 1 (4 loads each/wave)
  gll16(pA[0],      &As[0][ldsA[0]]);
  gll16(pA[1],      &As[0][ldsA[1]]);
  gll16(pG,         &Bg[0][dB]);
  gll16(pU,         &Bu[0][dB]);
  __builtin_amdgcn_sched_barrier(0);
  gll16(pA[0] + BK, &As[1][ldsA[0]]);
  gll16(pA[1] + BK, &As[1][ldsA[1]]);
  gll16(pG + BK,    &Bg[1][dB]);
  gll16(pU + BK,    &Bu[1][dB]);

  const int NT = HD / BK;   // 32 K-tiles
  for (int t = 0; t < NT; ++t) {
    int b = t % 3;
    // steady state: tiles t (4 loads) + t+1 (4 loads) outstanding; drain t's.
    if (t + 1 < NT) asm volatile("s_waitcnt vmcnt(4)" ::: "memory");
    else            asm volatile("s_waitcnt vmcnt(0)" ::: "memory");
    __builtin_amdgcn_sched_barrier(0);
    __builtin_amdgcn_s_barrier();   // tile t visible block-wide; t-1 reads done
    __builtin_amdgcn_sched_barrier(0);
    int k2 = (t + 2) * BK;
    if (k2 < HD) {
      int b2 = (t + 2) % 3;         // buffer read in iter t-1, now free
      gll16(pA[0] + k2, &As[b2][ldsA[0]]);
      gll16(pA[1] + k2, &As[b2][ldsA[1]]);
      gll16(pG + k2,    &Bg[b2][dB]);
      gll16(pU + k2,    &Bu[b2][dB]);
    }
    __builtin_amdgcn_sched_barrier(0);  // keep prefetch issues above compute
    short8 af[4], bgf[2], buf_[2];
#pragma unroll
    for (int i = 0; i < 4; ++i)
      af[i] = *(const short8*)(&As[b][(wm + i * 16 + m15) * BK + sl8]);
#pragma unroll
    for (int j = 0; j < 2; ++j) {
      bgf[j]  = *(const short8*)(&Bg[b][(wn + j * 16 + m15) * BK + sl8]);
      buf_[j] = *(const short8*)(&Bu[b][(wn + j * 16 + m15) * BK + sl8]);
    }
#pragma unroll
    for (int i = 0; i < 4; ++i)
#pragma unroll
      for (int j = 0; j < 2; ++j) {
        accg[i][j] = __builtin_amdgcn_mfma_f32_16x16x32_bf16(af[i], bgf[j],  accg[i][j], 0, 0, 0);
        accu[i][j] = __builtin_amdgcn_mfma_f32_16x16x32_bf16(af[i], buf_[j], accu[i][j], 0, 0, 0);
      }
    __builtin_amdgcn_sched_barrier(0);
  }

  int colB = n0 + wn + m15;
  int rowB = wm + ((lane >> 4) << 2);
#pragma unroll
  for (int i = 0; i < 4; ++i)
#pragma unroll
    for (int j = 0; j < 2; ++j)
#pragma unroll
      for (int r = 0; r < 4; ++r) {
        int lr = rowB + i * 16 + r;
        float g = accg[i][j][r], u = accu[i][j][r];
        float h = (grow0 + lr < segEnd) ? (g / (1.0f + __expf(-g))) * u : 0.0f;
        hbuf[(size_t)(hrow0 + lr) * DD + colB + j * 16] = f2bf(h);
      }
}

// ---------------- GEMM2: out[tok] += (hidden @ Wd^T) * wrow (atomic) ----------------
__global__ __launch_bounds__(256, 3) void k_gemm2(
    const unsigned short* __restrict__ hbuf,
    const unsigned short* __restrict__ wdt, const unsigned short* __restrict__ sdt,
    const int* __restrict__ tok, const int* __restrict__ tileE,
    const int* __restrict__ tileEnd, const float* __restrict__ wrow,
    float* __restrict__ outp, int tileBase) {
  // XCD swizzle: NX = HD/BM = 8
  int lin = blockIdx.y * 8 + blockIdx.x;
  int q = (8 * gridDim.y) >> 3;
  int wk = (lin & 7) * q + (lin >> 3);
  int bx = wk & 7, by = wk >> 3;

  int lt = by;
  int rt = tileBase + lt;
  int e = tileE[rt];
  if (e < 0) return;
  int n0 = bx * BM;
  int grow0 = rt * BM;
  int hrow0 = lt * BM;
  int segEnd = tileEnd[rt];
  const unsigned short* bd = (e == ED) ? sdt : wdt + (size_t)e * HD * DD;

  __shared__ __align__(16) unsigned short As[3][BM * BK];
  __shared__ __align__(16) unsigned short Bs[3][BM * BK];

  int tid = threadIdx.x, lane = tid & 63, wave = tid >> 6;
  int wm = (wave & 1) * 64, wn = (wave >> 1) * 64;
  int kc = (lane & 3) ^ ((lane >> 3) & 3);

  int ldsU[2];
  const unsigned short *pA[2], *pB[2];
#pragma unroll
  for (int r = 0; r < 2; ++r) {
    int chunk = r * 4 + wave;
    int row = chunk * 16 + (lane >> 2);
    ldsU[r] = chunk * 512;
    pA[r] = hbuf + (size_t)(hrow0 + row) * DD + kc * 8;
    pB[r] = bd + (size_t)(n0 + row) * DD + kc * 8;
  }

  f32x4 zero = {0.f, 0.f, 0.f, 0.f};
  f32x4 acc[4][4];
#pragma unroll
  for (int i = 0; i < 4; ++i)
#pragma unroll
    for (int j = 0; j < 4; ++j) acc[i][j] = zero;

  int m15 = lane & 15;
  int sl8 = (((lane >> 4) ^ ((lane >> 1) & 3)) * 8);

  // prologue: stage tiles 0 and 1 into buffers 0 and 1 (8 loads in flight/wave)
#pragma unroll
  for (int r = 0; r < 2; ++r) {
    gll16(pA[r], &As[0][ldsU[r]]);
    gll16(pB[r], &Bs[0][ldsU[r]]);
  }
#pragma unroll
  for (int r = 0; r < 2; ++r) {
    gll16(pA[r] + BK, &As[1][ldsU[r]]);
    gll16(pB[r] + BK, &Bs[1][ldsU[r]]);
  }

  for (int k0 = 0; k0 < DD; k0 += BK) {
    int ti = k0 >> 5;
    int b  = ti % 3;
    if (k0 + BK < DD) asm volatile("s_waitcnt vmcnt(4)" ::: "memory");
    else              asm volatile("s_waitcnt vmcnt(0)" ::: "memory");
    __builtin_amdgcn_sched_barrier(0);
    __builtin_amdgcn_s_barrier();
    __builtin_amdgcn_sched_barrier(0);
    int k2 = k0 + 2 * BK;
    if (k2 < DD) {
      int b2 = (ti + 2) % 3;
#pragma unroll
      for (int r = 0; r < 2; ++r) {
        gll16(pA[r] + k2, &As[b2][ldsU[r]]);
        gll16(pB[r] + k2, &Bs[b2][ldsU[r]]);
      }
    }
    __builtin_amdgcn_sched_barrier(0);  // keep prefetch issues above compute
    short8 af[4], bf[4];
#pragma unroll
    for (int i = 0; i < 4; ++i) {
      af[i] = *(const short8*)(&As[b][(wm + i * 16 + m15) * BK + sl8]);
      bf[i] = *(const short8*)(&Bs[b][(wn + i * 16 + m15) * BK + sl8]);
    }
#pragma unroll
    for (int i = 0; i < 4; ++i)
#pragma unroll
      for (int j = 0; j < 4; ++j)
        acc[i][j] = __builtin_amdgcn_mfma_f32_16x16x32_bf16(af[i], bf[j], acc[i][j], 0, 0, 0);
    __builtin_amdgcn_sched_barrier(0);
  }

  int colB = n0 + wn + m15;
  int rowB = wm + ((lane >> 4) << 2);
#pragma unroll
  for (int i = 0; i < 4; ++i)
#pragma unroll
    for (int r = 0; r < 4; ++r) {
      int grr = grow0 + rowB + i * 16 + r;
      if (grr < segEnd) {
        float w = wrow[grr];
        size_t ob = (size_t)tok[grr] * HD;
#pragma unroll
        for (int j = 0; j < 4; ++j)
          atomicAdd(&outp[ob + colB + j * 16], acc[i][j][r] * w);
      }
    }
}

extern "C" void kernel_launch(void* const* d_in, const int* in_sizes, int n_in,
                              void* d_out, int out_size, void* d_ws, size_t ws_size,
                              hipStream_t stream) {
  const float* x  = (const float*)d_in[0];
  const float* Wr = (const float*)d_in[1];
  const float* Wg = (const float*)d_in[2];
  const float* Wu = (const float*)d_in[3];
  const float* Wd = (const float*)d_in[4];
  const float* Sg = (const float*)d_in[5];
  const float* Su = (const float*)d_in[6];
  const float* Sd = (const float*)d_in[7];
  float* outp = (float*)d_out;

  // Fixed part of the workspace layout
  size_t fixed = 0;
  auto pad = [](size_t b) { return (b + 255) & ~(size_t)255; };
  fixed += pad((size_t)T_TOK * HD * 2);            // xb
  fixed += pad((size_t)ED * DD * HD * 2) * 3;      // wgt, wut, wdt
  fixed += pad((size_t)DD * HD * 2) * 3;           // sgt, sut, sdt
  fixed += pad((size_t)ROWCAP * 4) * 2;            // tok, wrow
  fixed += pad((size_t)T_TOK * 2 * 4) * 2;         // topE, topW
  fixed += pad(128) * 2 + pad(1024) * 2;           // counts, cursor, tileE, tileEnd
  // Adaptive chunking: single 200-tile pass if hbuf fits, else 2x100.
  int CH = TILE_MAX;
  if (fixed + pad((size_t)CH * BM * DD * 2) > ws_size) CH = TILE_MAX / 2;
  if (fixed + pad((size_t)CH * BM * DD * 2) > ws_size) return;  // diagnostic failure

  char* ws = (char*)d_ws;
  size_t off = 0;
  auto alloc = [&](size_t bytes) -> char* {
    char* p = ws + off;
    off += (bytes + 255) & ~(size_t)255;
    return p;
  };
  unsigned short* xb  = (unsigned short*)alloc((size_t)T_TOK * HD * 2);
  unsigned short* wgt = (unsigned short*)alloc((size_t)ED * DD * HD * 2);
  unsigned short* wut = (unsigned short*)alloc((size_t)ED * DD * HD * 2);
  unsigned short* wdt = (unsigned short*)alloc((size_t)ED * HD * DD * 2);
  unsigned short* sgt = (unsigned short*)alloc((size_t)DD * HD * 2);
  unsigned short* sut = (unsigned short*)alloc((size_t)DD * HD * 2);
  unsigned short* sdt = (unsigned short*)alloc((size_t)HD * DD * 2);
  int* tok       = (int*)alloc((size_t)ROWCAP * 4);
  float* wrow    = (float*)alloc((size_t)ROWCAP * 4);
  int* topE      = (int*)alloc((size_t)T_TOK * 2 * 4);
  float* topW    = (float*)alloc((size_t)T_TOK * 2 * 4);
  int* counts    = (int*)alloc(128);
  int* cursor    = (int*)alloc(128);
  int* tileE     = (int*)alloc(1024);
  int* tileEnd   = (int*)alloc(1024);
  unsigned short* hbuf = (unsigned short*)alloc((size_t)CH * BM * DD * 2);

  k_zero<<<(out_size / 4 + 255) / 256, 256, 0, stream>>>(outp);
  k_init<<<(ROWCAP + 255) / 256, 256, 0, stream>>>(counts, tok, wrow);
  k_transpose<<<dim3(DD / 64, HD / 64, ED), 256, 0, stream>>>(Wg, wgt, HD, DD);
  k_transpose<<<dim3(DD / 64, HD / 64, ED), 256, 0, stream>>>(Wu, wut, HD, DD);
  k_transpose<<<dim3(HD / 64, DD / 64, ED), 256, 0, stream>>>(Wd, wdt, DD, HD);
  k_transpose<<<dim3(DD / 64, HD / 64, 1), 256, 0, stream>>>(Sg, sgt, HD, DD);
  k_transpose<<<dim3(DD / 64, HD / 64, 1), 256, 0, stream>>>(Su, sut, HD, DD);
  k_transpose<<<dim3(HD / 64, DD / 64, 1), 256, 0, stream>>>(Sd, sdt, DD, HD);
  k_router<<<T_TOK / (4 * RT_TPW), 256, 0, stream>>>(x, Wr, xb, counts, topE, topW);
  k_plan<<<1, 256, 0, stream>>>(counts, cursor, tileE, tileEnd);
  k_scatter<<<T_TOK / 256, 256, 0, stream>>>(topE, topW, cursor, tok, wrow);
  for (int cb = 0; cb < TILE_MAX; cb += CH) {
    k_gemm1<<<dim3(DD / 64, CH), 256, 0, stream>>>(xb, wgt, wut, sgt, sut, tok,
                                                   tileE, tileEnd, hbuf, cb);
    k_gemm2<<<dim3(HD / BM, CH), 256, 0, stream>>>(hbuf, wdt, sdt, tok, tileE,
                                                   tileEnd, wrow, outp, cb);
  }
}